// Round 1
// baseline (1554.090 us; speedup 1.0000x reference)
//
#include <hip/hip_runtime.h>
#include <hip/hip_bf16.h>

#define NN 4096
#define R_RANK 10

// ---------------------------------------------------------------------------
// Adjacency pipeline: softmax(relu(nv1@nv2)) row-stats -> col degree -> AnT
// ---------------------------------------------------------------------------

__global__ __launch_bounds__(256) void row_stats_kernel(
    const float* __restrict__ nv1, const float* __restrict__ nv2,
    float* __restrict__ rowmax, float* __restrict__ rowsum)
{
    const int i = blockIdx.x;
    const int tid = threadIdx.x;
    __shared__ float a[R_RANK];
    __shared__ float red[4];
    if (tid < R_RANK) a[tid] = nv1[i * R_RANK + tid];
    __syncthreads();

    float s[16];
    float mx = 0.f;  // relu output >= 0, so 0 is the true lower bound of the max
    #pragma unroll
    for (int t = 0; t < 16; ++t) {
        const int j = t * 256 + tid;
        float acc = 0.f;
        #pragma unroll
        for (int r = 0; r < R_RANK; ++r) acc = fmaf(a[r], nv2[r * NN + j], acc);
        acc = fmaxf(acc, 0.f);
        s[t] = acc;
        mx = fmaxf(mx, acc);
    }
    #pragma unroll
    for (int off = 32; off > 0; off >>= 1) mx = fmaxf(mx, __shfl_down(mx, off, 64));
    if ((tid & 63) == 0) red[tid >> 6] = mx;
    __syncthreads();
    mx = fmaxf(fmaxf(red[0], red[1]), fmaxf(red[2], red[3]));

    float sum = 0.f;
    #pragma unroll
    for (int t = 0; t < 16; ++t) sum += __expf(s[t] - mx);
    #pragma unroll
    for (int off = 32; off > 0; off >>= 1) sum += __shfl_down(sum, off, 64);
    __syncthreads();  // red[] reads above must complete before rewrite
    if ((tid & 63) == 0) red[tid >> 6] = sum;
    __syncthreads();
    if (tid == 0) {
        rowmax[i] = mx;
        rowsum[i] = red[0] + red[1] + red[2] + red[3];
    }
}

// deg[j] += sum_i adp[i][j] over a 256-row slab (self-loop +1 added later)
__global__ __launch_bounds__(256) void col_sum_kernel(
    const float* __restrict__ nv1, const float* __restrict__ nv2,
    const float* __restrict__ rowmax, const float* __restrict__ rowsum,
    float* __restrict__ deg)
{
    const int j = blockIdx.x * 256 + threadIdx.x;
    const int i0 = blockIdx.y * 256;
    float v[R_RANK];
    #pragma unroll
    for (int r = 0; r < R_RANK; ++r) v[r] = nv2[r * NN + j];
    float acc = 0.f;
    for (int i = i0; i < i0 + 256; ++i) {
        float s = 0.f;
        #pragma unroll
        for (int r = 0; r < R_RANK; ++r) s = fmaf(nv1[i * R_RANK + r], v[r], s);
        s = fmaxf(s, 0.f);
        acc += __expf(s - rowmax[i]) * (1.0f / rowsum[i]);
    }
    atomicAdd(&deg[j], acc);
}

__global__ __launch_bounds__(256) void dinv_kernel(
    const float* __restrict__ deg, float* __restrict__ dinv)
{
    const int j = blockIdx.x * 256 + threadIdx.x;
    dinv[j] = rsqrtf(1.0f + deg[j]);  // +1 = self-loop; always > 0
}

// AnT[i][j] = (adp[j][i] + (i==j)) * dinv[i] * dinv[j]
__global__ __launch_bounds__(256) void an_build_kernel(
    const float* __restrict__ nv1, const float* __restrict__ nv2,
    const float* __restrict__ rowmax, const float* __restrict__ rowsum,
    const float* __restrict__ dinv, float* __restrict__ AnT)
{
    const int tid = threadIdx.x;
    const int j = blockIdx.x * 256 + tid;
    const int i0 = blockIdx.y * 8;
    __shared__ float v2s[8][R_RANK];
    __shared__ float dis[8];
    if (tid < 8 * R_RANK) {
        const int r = tid / 8, t = tid % 8;
        v2s[t][r] = nv2[r * NN + i0 + t];
    }
    if (tid < 8) dis[tid] = dinv[i0 + tid];

    float a[R_RANK];
    #pragma unroll
    for (int r = 0; r < R_RANK; ++r) a[r] = nv1[j * R_RANK + r];
    const float rm = rowmax[j];
    const float rs = 1.0f / rowsum[j];
    const float dj = dinv[j];
    __syncthreads();

    #pragma unroll
    for (int t = 0; t < 8; ++t) {
        const int i = i0 + t;
        float s = 0.f;
        #pragma unroll
        for (int r = 0; r < R_RANK; ++r) s = fmaf(a[r], v2s[t][r], s);
        s = fmaxf(s, 0.f);
        const float adp = __expf(s - rm) * rs;
        const float val = (adp + ((i == j) ? 1.f : 0.f)) * dis[t] * dj;
        AnT[(size_t)i * NN + j] = val;
    }
}

// ---------------------------------------------------------------------------
// fp32 tiled GEMM: C[M,Nc] = A[M,K] @ B[K,Nc], tile 128 x BN, BK=16.
// EPI: 0 = none, 1 = relu(x + bias), 2 = bn_eval(relu(x + bias))
// ---------------------------------------------------------------------------
template<int EPI, int BN>
__global__ __launch_bounds__(256) void gemm_tile(
    const float* __restrict__ A, const float* __restrict__ B,
    float* __restrict__ C, const int M, const int Nc, const int K,
    const float* __restrict__ bias, const float* __restrict__ gamma,
    const float* __restrict__ beta, const float* __restrict__ mean,
    const float* __restrict__ var)
{
    constexpr int MN = BN / 16;          // cols per thread (8 or 4)
    __shared__ float As[16][132];        // [k][m], +4 pad keeps 16B align, kills write conflicts
    __shared__ float Bs[16][BN];         // [k][n]
    const int tid = threadIdx.x;
    const int row0 = blockIdx.y * 128;
    const int col0 = blockIdx.x * BN;
    const int tx = tid & 15, ty = tid >> 4;

    float acc[8][MN];
    #pragma unroll
    for (int u = 0; u < 8; ++u)
        #pragma unroll
        for (int v = 0; v < MN; ++v) acc[u][v] = 0.f;

    const int arow = tid >> 2;           // 0..63
    const int ac4  = (tid & 3) << 2;     // 0,4,8,12
    const float* Ap0 = A + (size_t)(row0 + arow) * K + ac4;
    const float* Ap1 = A + (size_t)(row0 + arow + 64) * K + ac4;

    int brow, bcol;
    if constexpr (BN == 128) { brow = tid >> 5; bcol = (tid & 31) << 2; }
    else                     { brow = tid >> 4; bcol = (tid & 15) << 2; }
    const float* Bp0 = B + (size_t)brow * Nc + col0 + bcol;

    for (int k0 = 0; k0 < K; k0 += 16) {
        const float4 a0 = *(const float4*)(Ap0 + k0);
        const float4 a1 = *(const float4*)(Ap1 + k0);
        const float4 b0 = *(const float4*)(Bp0 + (size_t)k0 * Nc);
        float4 b1 = make_float4(0.f, 0.f, 0.f, 0.f);
        if constexpr (BN == 128) b1 = *(const float4*)(Bp0 + (size_t)(k0 + 8) * Nc);

        __syncthreads();  // previous iter's LDS reads must finish
        As[ac4 + 0][arow] = a0.x; As[ac4 + 1][arow] = a0.y;
        As[ac4 + 2][arow] = a0.z; As[ac4 + 3][arow] = a0.w;
        As[ac4 + 0][arow + 64] = a1.x; As[ac4 + 1][arow + 64] = a1.y;
        As[ac4 + 2][arow + 64] = a1.z; As[ac4 + 3][arow + 64] = a1.w;
        *(float4*)&Bs[brow][bcol] = b0;
        if constexpr (BN == 128) *(float4*)&Bs[brow + 8][bcol] = b1;
        __syncthreads();

        #pragma unroll
        for (int kk = 0; kk < 16; ++kk) {
            float av[8], bv[MN];
            *(float4*)&av[0] = *(const float4*)&As[kk][ty * 8];
            *(float4*)&av[4] = *(const float4*)&As[kk][ty * 8 + 4];
            *(float4*)&bv[0] = *(const float4*)&Bs[kk][tx * MN];
            if constexpr (MN == 8) *(float4*)&bv[4] = *(const float4*)&Bs[kk][tx * MN + 4];
            #pragma unroll
            for (int u = 0; u < 8; ++u)
                #pragma unroll
                for (int v = 0; v < MN; ++v)
                    acc[u][v] = fmaf(av[u], bv[v], acc[u][v]);
        }
    }

    // epilogue
    float bcolv[MN], scale[MN], shift[MN];
    #pragma unroll
    for (int v = 0; v < MN; ++v) {
        const int cI = col0 + tx * MN + v;
        if constexpr (EPI >= 1) bcolv[v] = bias[cI];
        if constexpr (EPI == 2) {
            const float inv = rsqrtf(var[cI] + 1e-5f);
            const float sc = gamma[cI] * inv;
            scale[v] = sc;
            shift[v] = fmaf(-mean[cI], sc, beta[cI]);
        }
    }
    #pragma unroll
    for (int u = 0; u < 8; ++u) {
        const int row = row0 + ty * 8 + u;
        float vals[MN];
        #pragma unroll
        for (int v = 0; v < MN; ++v) {
            float xv = acc[u][v];
            if constexpr (EPI >= 1) xv = fmaxf(xv + bcolv[v], 0.f);
            if constexpr (EPI == 2) xv = fmaf(xv, scale[v], shift[v]);
            vals[v] = xv;
        }
        float4* cp = (float4*)(C + (size_t)row * Nc + col0 + tx * MN);
        cp[0] = make_float4(vals[0], vals[1], vals[2], vals[3]);
        if constexpr (MN == 8) cp[1] = make_float4(vals[4], vals[5], vals[6], vals[7]);
    }
}

// ---------------------------------------------------------------------------
// Pool + attention
// ---------------------------------------------------------------------------
__global__ __launch_bounds__(256) void pool_partial_kernel(
    const float* __restrict__ h2, float* __restrict__ pooled)
{
    const int c = blockIdx.x * 256 + threadIdx.x;   // 0..511
    const int i0 = blockIdx.y * 64;
    float acc = 0.f;
    for (int i = i0; i < i0 + 64; ++i) acc += h2[(size_t)i * 512 + c];
    atomicAdd(&pooled[c], acc);
}

__global__ __launch_bounds__(512) void finalize_kernel(
    const float* __restrict__ pooled, const float* __restrict__ w_attn,
    const float* __restrict__ b_attn, float* __restrict__ out)
{
    const int c = threadIdx.x;  // 512 threads
    __shared__ float red[512];
    const float p = pooled[c] * (1.0f / 4096.0f);
    red[c] = p * w_attn[c];
    __syncthreads();
    for (int s = 256; s > 0; s >>= 1) {
        if (c < s) red[c] += red[c + s];
        __syncthreads();
    }
    const float attn = 1.0f / (1.0f + __expf(-(red[0] + b_attn[0])));
    out[c] = p * attn;
}

// ---------------------------------------------------------------------------
extern "C" void kernel_launch(void* const* d_in, const int* in_sizes, int n_in,
                              void* d_out, int out_size, void* d_ws, size_t ws_size,
                              hipStream_t stream) {
    const float* x      = (const float*)d_in[0];
    const float* w_map  = (const float*)d_in[1];
    const float* b_map  = (const float*)d_in[2];
    const float* nv1    = (const float*)d_in[3];
    const float* nv2    = (const float*)d_in[4];
    const float* w1     = (const float*)d_in[5];
    const float* b1     = (const float*)d_in[6];
    const float* w2     = (const float*)d_in[7];
    const float* b2     = (const float*)d_in[8];
    const float* bn1_g  = (const float*)d_in[9];
    const float* bn1_b  = (const float*)d_in[10];
    const float* bn1_m  = (const float*)d_in[11];
    const float* bn1_v  = (const float*)d_in[12];
    const float* bn2_g  = (const float*)d_in[13];
    const float* bn2_b  = (const float*)d_in[14];
    const float* bn2_m  = (const float*)d_in[15];
    const float* bn2_v  = (const float*)d_in[16];
    const float* w_attn = (const float*)d_in[17];
    const float* b_attn = (const float*)d_in[18];
    float* out = (float*)d_out;

    // workspace layout (~96.1 MB total)
    char* ws = (char*)d_ws;
    float* AnT    = (float*)(ws);                               // 4096*4096*4 = 64 MB
    float* bufA   = (float*)(ws + (size_t)67108864);            // 16 MB (xm -> h1 -> h2)
    float* bufB   = (float*)(ws + (size_t)67108864 + 16777216); // 16 MB (t1 -> t2)
    float* deg    = (float*)(ws + (size_t)100663296);
    float* dinv   = deg + 4096;
    float* rowmax = dinv + 4096;
    float* rowsum = rowmax + 4096;
    float* pooled = rowsum + 4096;

    // adjacency
    row_stats_kernel<<<NN, 256, 0, stream>>>(nv1, nv2, rowmax, rowsum);
    hipMemsetAsync(deg, 0, 4096 * sizeof(float), stream);
    col_sum_kernel<<<dim3(16, 16), 256, 0, stream>>>(nv1, nv2, rowmax, rowsum, deg);
    dinv_kernel<<<16, 256, 0, stream>>>(deg, dinv);
    an_build_kernel<<<dim3(16, 512), 256, 0, stream>>>(nv1, nv2, rowmax, rowsum, dinv, AnT);

    // xm = relu(x @ w_map + b_map)                      [4096,1024]
    gemm_tile<1, 128><<<dim3(8, 32), 256, 0, stream>>>(
        x, w_map, bufA, 4096, 1024, 1024, b_map, nullptr, nullptr, nullptr, nullptr);
    // t1 = xm @ w1                                      [4096,1024]
    gemm_tile<0, 128><<<dim3(8, 32), 256, 0, stream>>>(
        bufA, w1, bufB, 4096, 1024, 1024, nullptr, nullptr, nullptr, nullptr, nullptr);
    // h1 = bn1(relu(AnT @ t1 + b1))                     [4096,1024]
    gemm_tile<2, 128><<<dim3(8, 32), 256, 0, stream>>>(
        AnT, bufB, bufA, 4096, 1024, 4096, b1, bn1_g, bn1_b, bn1_m, bn1_v);
    // t2 = h1 @ w2                                      [4096,512]
    gemm_tile<0, 64><<<dim3(8, 32), 256, 0, stream>>>(
        bufA, w2, bufB, 4096, 512, 1024, nullptr, nullptr, nullptr, nullptr, nullptr);
    // h2 = bn2(relu(AnT @ t2 + b2))                     [4096,512]
    gemm_tile<2, 64><<<dim3(8, 32), 256, 0, stream>>>(
        AnT, bufB, bufA, 4096, 512, 4096, b2, bn2_g, bn2_b, bn2_m, bn2_v);

    // pooled mean + attention
    hipMemsetAsync(pooled, 0, 512 * sizeof(float), stream);
    pool_partial_kernel<<<dim3(2, 64), 256, 0, stream>>>(bufA, pooled);
    finalize_kernel<<<1, 512, 0, stream>>>(pooled, w_attn, b_attn, out);
}

// Round 2
// 405.048 us; speedup vs baseline: 3.8368x; 3.8368x over previous
//
#include <hip/hip_runtime.h>

#define NN 4096
#define R_RANK 10

typedef __bf16 bf16x8 __attribute__((ext_vector_type(8)));
typedef float floatx4 __attribute__((ext_vector_type(4)));

__device__ __forceinline__ unsigned short f2bf(float f) {
    union { float f; unsigned int u; } v; v.f = f;
    unsigned int r = v.u + 0x7FFFu + ((v.u >> 16) & 1u);   // RNE
    return (unsigned short)(r >> 16);
}
__device__ __forceinline__ float bf2f(unsigned short b) {
    union { unsigned int u; float f; } v; v.u = ((unsigned int)b) << 16;
    return v.f;
}
// async global->LDS, 16B per lane; LDS dest = wave-uniform base + lane*16
__device__ __forceinline__ void gll16(const void* g, void* l) {
    __builtin_amdgcn_global_load_lds(
        (const __attribute__((address_space(1))) unsigned int*)g,
        (__attribute__((address_space(3))) unsigned int*)l, 16, 0, 0);
}

// ---------------------------------------------------------------------------
// Adjacency pipeline (unchanged math; AnT now written in bf16)
// ---------------------------------------------------------------------------
__global__ __launch_bounds__(256) void row_stats_kernel(
    const float* __restrict__ nv1, const float* __restrict__ nv2,
    float* __restrict__ rowmax, float* __restrict__ rowsum)
{
    const int i = blockIdx.x;
    const int tid = threadIdx.x;
    __shared__ float a[R_RANK];
    __shared__ float red[4];
    if (tid < R_RANK) a[tid] = nv1[i * R_RANK + tid];
    __syncthreads();

    float s[16];
    float mx = 0.f;
    #pragma unroll
    for (int t = 0; t < 16; ++t) {
        const int j = t * 256 + tid;
        float acc = 0.f;
        #pragma unroll
        for (int r = 0; r < R_RANK; ++r) acc = fmaf(a[r], nv2[r * NN + j], acc);
        acc = fmaxf(acc, 0.f);
        s[t] = acc;
        mx = fmaxf(mx, acc);
    }
    #pragma unroll
    for (int off = 32; off > 0; off >>= 1) mx = fmaxf(mx, __shfl_down(mx, off, 64));
    if ((tid & 63) == 0) red[tid >> 6] = mx;
    __syncthreads();
    mx = fmaxf(fmaxf(red[0], red[1]), fmaxf(red[2], red[3]));

    float sum = 0.f;
    #pragma unroll
    for (int t = 0; t < 16; ++t) sum += __expf(s[t] - mx);
    #pragma unroll
    for (int off = 32; off > 0; off >>= 1) sum += __shfl_down(sum, off, 64);
    __syncthreads();
    if ((tid & 63) == 0) red[tid >> 6] = sum;
    __syncthreads();
    if (tid == 0) {
        rowmax[i] = mx;
        rowsum[i] = red[0] + red[1] + red[2] + red[3];
    }
}

__global__ __launch_bounds__(256) void col_sum_kernel(
    const float* __restrict__ nv1, const float* __restrict__ nv2,
    const float* __restrict__ rowmax, const float* __restrict__ rowsum,
    float* __restrict__ deg)
{
    const int j = blockIdx.x * 256 + threadIdx.x;
    const int i0 = blockIdx.y * 256;
    float v[R_RANK];
    #pragma unroll
    for (int r = 0; r < R_RANK; ++r) v[r] = nv2[r * NN + j];
    float acc = 0.f;
    for (int i = i0; i < i0 + 256; ++i) {
        float s = 0.f;
        #pragma unroll
        for (int r = 0; r < R_RANK; ++r) s = fmaf(nv1[i * R_RANK + r], v[r], s);
        s = fmaxf(s, 0.f);
        acc += __expf(s - rowmax[i]) * (1.0f / rowsum[i]);
    }
    atomicAdd(&deg[j], acc);
}

__global__ __launch_bounds__(256) void dinv_kernel(
    const float* __restrict__ deg, float* __restrict__ dinv)
{
    const int j = blockIdx.x * 256 + threadIdx.x;
    dinv[j] = rsqrtf(1.0f + deg[j]);
}

__global__ __launch_bounds__(256) void an_build_kernel(
    const float* __restrict__ nv1, const float* __restrict__ nv2,
    const float* __restrict__ rowmax, const float* __restrict__ rowsum,
    const float* __restrict__ dinv, unsigned short* __restrict__ AnT)
{
    const int tid = threadIdx.x;
    const int j = blockIdx.x * 256 + tid;
    const int i0 = blockIdx.y * 8;
    __shared__ float v2s[8][R_RANK];
    __shared__ float dis[8];
    if (tid < 8 * R_RANK) {
        const int r = tid / 8, t = tid % 8;
        v2s[t][r] = nv2[r * NN + i0 + t];
    }
    if (tid < 8) dis[tid] = dinv[i0 + tid];

    float a[R_RANK];
    #pragma unroll
    for (int r = 0; r < R_RANK; ++r) a[r] = nv1[j * R_RANK + r];
    const float rm = rowmax[j];
    const float rs = 1.0f / rowsum[j];
    const float dj = dinv[j];
    __syncthreads();

    #pragma unroll
    for (int t = 0; t < 8; ++t) {
        const int i = i0 + t;
        float s = 0.f;
        #pragma unroll
        for (int r = 0; r < R_RANK; ++r) s = fmaf(a[r], v2s[t][r], s);
        s = fmaxf(s, 0.f);
        const float adp = __expf(s - rm) * rs;
        const float val = (adp + ((i == j) ? 1.f : 0.f)) * dis[t] * dj;
        AnT[(size_t)i * NN + j] = f2bf(val);
    }
}

// ---------------------------------------------------------------------------
// fp32 -> bf16 converters
// ---------------------------------------------------------------------------
__global__ __launch_bounds__(256) void cvt_bf16_kernel(
    const float* __restrict__ src, unsigned short* __restrict__ dst)
{
    const size_t i = ((size_t)blockIdx.x * 256 + threadIdx.x) * 8;
    const float4 a = *(const float4*)(src + i);
    const float4 b = *(const float4*)(src + i + 4);
    ushort4 p, q;
    p.x = f2bf(a.x); p.y = f2bf(a.y); p.z = f2bf(a.z); p.w = f2bf(a.w);
    q.x = f2bf(b.x); q.y = f2bf(b.y); q.z = f2bf(b.z); q.w = f2bf(b.w);
    *(ushort4*)(dst + i) = p;
    *(ushort4*)(dst + i + 4) = q;
}

// W [RK][CN] fp32 -> WT [CN][RK] bf16
__global__ __launch_bounds__(256) void wt_kernel(
    const float* __restrict__ W, unsigned short* __restrict__ WT,
    const int RK, const int CN)
{
    __shared__ float s[32][33];
    const int tid = threadIdx.x;
    const int tx = tid & 31, ty = tid >> 5;       // ty 0..7
    const int r0 = blockIdx.y * 32, c0 = blockIdx.x * 32;
    #pragma unroll
    for (int i = 0; i < 4; ++i)
        s[ty + 8 * i][tx] = W[(size_t)(r0 + ty + 8 * i) * CN + c0 + tx];
    __syncthreads();
    #pragma unroll
    for (int i = 0; i < 4; ++i)
        WT[(size_t)(c0 + ty + 8 * i) * RK + r0 + tx] = f2bf(s[tx][ty + 8 * i]);
}

// ---------------------------------------------------------------------------
// bf16 MFMA GEMM: C = A[M,K] @ Bt[N,K]^T, fp32 accumulate.
// Tile 64 x BNT, BK=32, 256 threads = 4 waves (2x2), wave tile 32 x (BNT/2).
// EPI: 0 none, 1 relu(x+bias), 2 bn(relu(x+bias)).  TRANS: 0 -> C[M,N], 1 -> C[N,M]
// ---------------------------------------------------------------------------
template<int EPI, int BNT, int TRANS>
__global__ __launch_bounds__(256) void gemm_bf16(
    const unsigned short* __restrict__ A, const unsigned short* __restrict__ Bt,
    unsigned short* __restrict__ C, const int M, const int N, const int K,
    const float* __restrict__ bias, const float* __restrict__ gamma,
    const float* __restrict__ beta, const float* __restrict__ mean,
    const float* __restrict__ var)
{
    constexpr int NF = BNT / 32;     // n-frags per wave
    constexpr int NBCH = BNT / 64;   // B LDS chunks per wave
    __shared__ __align__(16) unsigned short As[64 * 32];
    __shared__ __align__(16) unsigned short Bs[BNT * 32];
    const int tid = threadIdx.x;
    const int l = tid & 63, w = tid >> 6;
    const int wy = w >> 1, wx = w & 1;
    const int row0 = blockIdx.y * 64;
    const int col0 = blockIdx.x * BNT;

    // staging: each lane loads 16B; LDS slot = wave base + lane*16
    const size_t a_goff = (size_t)(row0 + 16 * w + (l >> 2)) * K + (size_t)(l & 3) * 8;
    size_t b_goff[NBCH];
    #pragma unroll
    for (int i = 0; i < NBCH; ++i)
        b_goff[i] = (size_t)(col0 + 16 * (w + 4 * i) + (l >> 2)) * K + (size_t)(l & 3) * 8;

    floatx4 acc[2][NF];
    #pragma unroll
    for (int mf = 0; mf < 2; ++mf)
        #pragma unroll
        for (int nf = 0; nf < NF; ++nf) acc[mf][nf] = (floatx4){0.f, 0.f, 0.f, 0.f};

    // fragment LDS offsets (elements): row*32 + quad*8
    const int a_roff = (wy * 32 + (l & 15)) * 32 + (l >> 4) * 8;
    const int b_roff = (wx * NF * 16 + (l & 15)) * 32 + (l >> 4) * 8;

    for (int k0 = 0; k0 < K; k0 += 32) {
        __syncthreads();                       // WAR: prev iter's reads done
        gll16(A + a_goff + k0, &As[w * 512]);
        #pragma unroll
        for (int i = 0; i < NBCH; ++i)
            gll16(Bt + b_goff[i] + k0, &Bs[(w + 4 * i) * 512]);
        __syncthreads();                       // drains vmcnt: tile ready

        bf16x8 af[2], bv[NF];
        #pragma unroll
        for (int mf = 0; mf < 2; ++mf) af[mf] = *(const bf16x8*)&As[a_roff + mf * 512];
        #pragma unroll
        for (int nf = 0; nf < NF; ++nf) bv[nf] = *(const bf16x8*)&Bs[b_roff + nf * 512];
        #pragma unroll
        for (int mf = 0; mf < 2; ++mf)
            #pragma unroll
            for (int nf = 0; nf < NF; ++nf)
                acc[mf][nf] = __builtin_amdgcn_mfma_f32_16x16x32_bf16(
                    af[mf], bv[nf], acc[mf][nf], 0, 0, 0);
    }

    // epilogue: C/D layout col=lane&15, row=(lane>>4)*4+reg
    float bias_v[NF], sc[NF], sh[NF];
    int gcol[NF];
    #pragma unroll
    for (int nf = 0; nf < NF; ++nf) {
        gcol[nf] = col0 + wx * NF * 16 + nf * 16 + (l & 15);
        if constexpr (EPI >= 1) bias_v[nf] = bias[gcol[nf]];
        if constexpr (EPI == 2) {
            const float inv = rsqrtf(var[gcol[nf]] + 1e-5f);
            sc[nf] = gamma[gcol[nf]] * inv;
            sh[nf] = beta[gcol[nf]] - mean[gcol[nf]] * sc[nf];
        }
    }
    const int gr0 = row0 + wy * 32 + (l >> 4) * 4;
    #pragma unroll
    for (int mf = 0; mf < 2; ++mf) {
        const int gr = gr0 + mf * 16;
        #pragma unroll
        for (int nf = 0; nf < NF; ++nf) {
            float vals[4];
            #pragma unroll
            for (int r = 0; r < 4; ++r) {
                float x = acc[mf][nf][r];
                if constexpr (EPI >= 1) x = fmaxf(x + bias_v[nf], 0.f);
                if constexpr (EPI == 2) x = fmaf(x, sc[nf], sh[nf]);
                vals[r] = x;
            }
            if constexpr (TRANS == 0) {
                #pragma unroll
                for (int r = 0; r < 4; ++r)
                    C[(size_t)(gr + r) * N + gcol[nf]] = f2bf(vals[r]);
            } else {
                ushort4 p;
                p.x = f2bf(vals[0]); p.y = f2bf(vals[1]);
                p.z = f2bf(vals[2]); p.w = f2bf(vals[3]);
                *(ushort4*)&C[(size_t)gcol[nf] * M + gr] = p;   // contiguous 8B
            }
        }
    }
}

// ---------------------------------------------------------------------------
// Pool (h2 stored transposed [COUT][NN]) + attention
// ---------------------------------------------------------------------------
__global__ __launch_bounds__(256) void pool_kernel(
    const unsigned short* __restrict__ h2T, float* __restrict__ pooled)
{
    const int c = blockIdx.x;      // 0..511
    const int tid = threadIdx.x;
    const uint4* p = (const uint4*)(h2T + (size_t)c * NN) + tid * 2;
    float s = 0.f;
    #pragma unroll
    for (int i = 0; i < 2; ++i) {
        const uint4 q = p[i];
        const unsigned int arr[4] = {q.x, q.y, q.z, q.w};
        #pragma unroll
        for (int j = 0; j < 4; ++j) {
            s += bf2f((unsigned short)(arr[j] & 0xFFFFu));
            s += bf2f((unsigned short)(arr[j] >> 16));
        }
    }
    __shared__ float red[4];
    #pragma unroll
    for (int off = 32; off > 0; off >>= 1) s += __shfl_down(s, off, 64);
    if ((tid & 63) == 0) red[tid >> 6] = s;
    __syncthreads();
    if (tid == 0) pooled[c] = (red[0] + red[1] + red[2] + red[3]) * (1.0f / 4096.0f);
}

__global__ __launch_bounds__(512) void finalize_kernel(
    const float* __restrict__ pooled, const float* __restrict__ w_attn,
    const float* __restrict__ b_attn, float* __restrict__ out)
{
    const int c = threadIdx.x;
    __shared__ float red[512];
    const float p = pooled[c];
    red[c] = p * w_attn[c];
    __syncthreads();
    for (int s = 256; s > 0; s >>= 1) {
        if (c < s) red[c] += red[c + s];
        __syncthreads();
    }
    const float attn = 1.0f / (1.0f + __expf(-(red[0] + b_attn[0])));
    out[c] = p * attn;
}

// ---------------------------------------------------------------------------
extern "C" void kernel_launch(void* const* d_in, const int* in_sizes, int n_in,
                              void* d_out, int out_size, void* d_ws, size_t ws_size,
                              hipStream_t stream) {
    const float* x      = (const float*)d_in[0];
    const float* w_map  = (const float*)d_in[1];
    const float* b_map  = (const float*)d_in[2];
    const float* nv1    = (const float*)d_in[3];
    const float* nv2    = (const float*)d_in[4];
    const float* w1     = (const float*)d_in[5];
    const float* b1     = (const float*)d_in[6];
    const float* w2     = (const float*)d_in[7];
    const float* b2     = (const float*)d_in[8];
    const float* bn1_g  = (const float*)d_in[9];
    const float* bn1_b  = (const float*)d_in[10];
    const float* bn1_m  = (const float*)d_in[11];
    const float* bn1_v  = (const float*)d_in[12];
    const float* bn2_g  = (const float*)d_in[13];
    const float* bn2_b  = (const float*)d_in[14];
    const float* bn2_m  = (const float*)d_in[15];
    const float* bn2_v  = (const float*)d_in[16];
    const float* w_attn = (const float*)d_in[17];
    const float* b_attn = (const float*)d_in[18];
    float* out = (float*)d_out;

    // workspace (bytes)
    char* ws = (char*)d_ws;
    unsigned short* AnT   = (unsigned short*)(ws);                    // 32 MB  [4096][4096]
    unsigned short* xb    = (unsigned short*)(ws + 33554432);         //  8 MB  [4096][1024]
    unsigned short* xm    = (unsigned short*)(ws + 41943040);         //  8 MB  [4096][1024]
    unsigned short* t1T   = (unsigned short*)(ws + 50331648);         //  8 MB  [1024][4096]
    unsigned short* h1    = (unsigned short*)(ws + 58720256);         //  8 MB  [4096][1024]
    unsigned short* t2T   = (unsigned short*)(ws + 67108864);         //  4 MB  [512][4096]
    unsigned short* h2T   = (unsigned short*)(ws + 71303168);         //  4 MB  [512][4096]
    unsigned short* wmT   = (unsigned short*)(ws + 75497472);         //  2 MB  [1024][1024]
    unsigned short* w1T   = (unsigned short*)(ws + 77594624);         //  2 MB  [1024][1024]
    unsigned short* w2T   = (unsigned short*)(ws + 79691776);         //  1 MB  [512][1024]
    float* deg    = (float*)(ws + 80740352);
    float* dinv   = deg + 4096;
    float* rowmax = dinv + 4096;
    float* rowsum = rowmax + 4096;
    float* pooled = rowsum + 4096;

    // adjacency (fp32 math, bf16 AnT out)
    row_stats_kernel<<<NN, 256, 0, stream>>>(nv1, nv2, rowmax, rowsum);
    hipMemsetAsync(deg, 0, 4096 * sizeof(float), stream);
    col_sum_kernel<<<dim3(16, 16), 256, 0, stream>>>(nv1, nv2, rowmax, rowsum, deg);
    dinv_kernel<<<16, 256, 0, stream>>>(deg, dinv);
    an_build_kernel<<<dim3(16, 512), 256, 0, stream>>>(nv1, nv2, rowmax, rowsum, dinv, AnT);

    // conversions
    cvt_bf16_kernel<<<2048, 256, 0, stream>>>(x, xb);                       // x -> bf16
    wt_kernel<<<dim3(32, 32), 256, 0, stream>>>(w_map, wmT, 1024, 1024);    // w_map^T
    wt_kernel<<<dim3(32, 32), 256, 0, stream>>>(w1, w1T, 1024, 1024);       // w1^T
    wt_kernel<<<dim3(16, 32), 256, 0, stream>>>(w2, w2T, 1024, 512);        // w2^T

    // G1: xm = relu(x @ w_map + b_map)              [4096,1024] row-major
    gemm_bf16<1, 128, 0><<<dim3(8, 64), 256, 0, stream>>>(
        xb, wmT, xm, 4096, 1024, 1024, b_map, nullptr, nullptr, nullptr, nullptr);
    // G2: t1 = xm @ w1, stored transposed           t1T [1024][4096]
    gemm_bf16<0, 128, 1><<<dim3(8, 64), 256, 0, stream>>>(
        xm, w1T, t1T, 4096, 1024, 1024, nullptr, nullptr, nullptr, nullptr, nullptr);
    // G3: h1 = bn1(relu(AnT @ t1 + b1))             [4096,1024] row-major
    gemm_bf16<2, 128, 0><<<dim3(8, 64), 256, 0, stream>>>(
        AnT, t1T, h1, 4096, 1024, 4096, b1, bn1_g, bn1_b, bn1_m, bn1_v);
    // G4: t2 = h1 @ w2, stored transposed           t2T [512][4096]
    gemm_bf16<0, 64, 1><<<dim3(8, 64), 256, 0, stream>>>(
        h1, w2T, t2T, 4096, 512, 1024, nullptr, nullptr, nullptr, nullptr, nullptr);
    // G5: h2 = bn2(relu(AnT @ t2 + b2)), transposed h2T [512][4096]
    gemm_bf16<2, 64, 1><<<dim3(8, 64), 256, 0, stream>>>(
        AnT, t2T, h2T, 4096, 512, 4096, b2, bn2_g, bn2_b, bn2_m, bn2_v);

    // pool + attention
    pool_kernel<<<512, 256, 0, stream>>>(h2T, pooled);
    finalize_kernel<<<1, 512, 0, stream>>>(pooled, w_attn, b_attn, out);
}